// Round 4
// baseline (625.362 us; speedup 1.0000x reference)
//
#include <hip/hip_runtime.h>
#include <math.h>

// Problem constants (shapes fixed by setup_inputs: e_n=4096, v_n=16384, kn=10)
#define VN 16384
#define EN 4096
#define TPB 256
#define CHUNKS 16        // 16 x float4 per thread = 64 elems; 256*64 = 16384
#define BLEND_BLOCKS 2048
#define BLEND_T ((long long)BLEND_BLOCKS * TPB)   // 524288 threads
// n4 = VN*VN/4 = 67,108,864 float4 = BLEND_T * 128 exactly

typedef float f32x4 __attribute__((ext_vector_type(4)));

// ---------------------------------------------------------------------------
// Per-row top-k (k iterative argmax rounds over register-resident row) +
// DV accumulation. Tie-break = (max value, lowest index), matching
// jax.lax.top_k; softmax is monotone so top-k of raw logits == top-k of the
// double-softmax. Owner-only rescan keeps the per-round VALU cost low.
// ---------------------------------------------------------------------------
__global__ __launch_bounds__(TPB) void topk_dv_kernel(
    const float* __restrict__ vam, const int* __restrict__ kn_ptr,
    int* __restrict__ dv, int* __restrict__ topk)
{
    const int e = blockIdx.x;
    const int t = threadIdx.x;
    const float* row = vam + (size_t)e * VN;

    // Stage the row into registers: thread t owns elements c*1024 + 4t + j
    float v[CHUNKS][4];
#pragma unroll
    for (int c = 0; c < CHUNKS; ++c) {
        const float4 f = *reinterpret_cast<const float4*>(row + c * (TPB * 4) + t * 4);
        v[c][0] = f.x; v[c][1] = f.y; v[c][2] = f.z; v[c][3] = f.w;
    }

    int kn = kn_ptr[0];
    if (kn > 32) kn = 32;   // workspace guard

    __shared__ unsigned long long wred[TPB / 64];
    __shared__ int bcast;

    // cached local best; strict > keeps the lowest index on exact ties
    float bv = -INFINITY;
    int   bi = 0;
#pragma unroll
    for (int c = 0; c < CHUNKS; ++c) {
#pragma unroll
        for (int j = 0; j < 4; ++j) {
            const int gi = c * (TPB * 4) + t * 4 + j;
            if (v[c][j] > bv) { bv = v[c][j]; bi = gi; }
        }
    }

    for (int r = 0; r < kn; ++r) {
        // pack (value, index): u64 max == (max value, min index)
        unsigned int uv = __float_as_uint(bv);
        uv = (uv & 0x80000000u) ? ~uv : (uv | 0x80000000u);  // order-preserving
        unsigned long long key =
            ((unsigned long long)uv << 32) | (unsigned int)(~(unsigned int)bi);

#pragma unroll
        for (int s = 1; s < 64; s <<= 1) {
            const unsigned long long o = __shfl_xor(key, s, 64);
            if (o > key) key = o;
        }
        if ((t & 63) == 0) wred[t >> 6] = key;
        __syncthreads();
        if (t == 0) {
            unsigned long long kmax = wred[0];
#pragma unroll
            for (int w = 1; w < TPB / 64; ++w) if (wred[w] > kmax) kmax = wred[w];
            const int wi = (int)(~(unsigned int)(kmax & 0xffffffffull));
            bcast = wi;
            topk[(size_t)e * kn + r] = wi;
            atomicAdd(dv + wi, 1);
        }
        __syncthreads();
        const int wi = bcast;

        // only the owner thread pays the removal + rescan
        if (((wi >> 2) & (TPB - 1)) == t) {
#pragma unroll
            for (int c = 0; c < CHUNKS; ++c) {
#pragma unroll
                for (int j = 0; j < 4; ++j) {
                    const int gi = c * (TPB * 4) + t * 4 + j;
                    if (gi == wi) v[c][j] = -INFINITY;
                }
            }
            bv = -INFINITY; bi = 0;
#pragma unroll
            for (int c = 0; c < CHUNKS; ++c) {
#pragma unroll
                for (int j = 0; j < 4; ++j) {
                    const int gi = c * (TPB * 4) + t * 4 + j;
                    if (v[c][j] > bv) { bv = v[c][j]; bi = gi; }
                }
            }
        }
        __syncthreads();  // protect wred/bcast reuse next round
    }
}

// invDV[v] = DV[v] > 0 ? DV[v]^-0.5 : 0
__global__ void invdv_kernel(const int* __restrict__ dv, float* __restrict__ invdv)
{
    const int v = blockIdx.x * blockDim.x + threadIdx.x;
    if (v < VN) {
        const int d = dv[v];
        invdv[v] = d > 0 ? 1.0f / sqrtf((float)d) : 0.0f;
    }
}

// ---------------------------------------------------------------------------
// out = 0.5 * G. Standalone streaming kernel: low VGPR -> full 8 waves/SIMD
// occupancy (de-fused from top-k so its register budget doesn't cap us),
// 8-deep load batches, non-temporal hints (G and out are stream-once here).
// ---------------------------------------------------------------------------
__global__ __launch_bounds__(TPB) void blend_kernel(
    const f32x4* __restrict__ g, f32x4* __restrict__ out)
{
    const long long tid = (long long)blockIdx.x * TPB + threadIdx.x;
    f32x4 x[8];
    for (int m = 0; m < 128; m += 8) {
#pragma unroll
        for (int u = 0; u < 8; ++u)
            x[u] = __builtin_nontemporal_load(&g[tid + (long long)(m + u) * BLEND_T]);
#pragma unroll
        for (int u = 0; u < 8; ++u)
            __builtin_nontemporal_store(x[u] * 0.5f,
                                        &out[tid + (long long)(m + u) * BLEND_T]);
    }
}

// out[a][b] += 0.5 * invDV[a]*invDV[b]*(1/kn) for every pair (a,b) in each
// edge's top-k set (includes a==b, both orders -> symmetric, diag included).
__global__ void scatter_kernel(const int* __restrict__ topk,
                               const float* __restrict__ invdv,
                               const int* __restrict__ kn_ptr,
                               float* __restrict__ out)
{
    const int e = blockIdx.x;
    int kn = kn_ptr[0];
    if (kn > 32) kn = 32;
    const int total = kn * kn;
    const float inv_de = 1.0f / (float)kn;
    for (int p = threadIdx.x; p < total; p += blockDim.x) {
        const int a = topk[(size_t)e * kn + p / kn];
        const int b = topk[(size_t)e * kn + p % kn];
        const float c = 0.5f * invdv[a] * invdv[b] * inv_de;
        atomicAdd(out + (size_t)a * VN + b, c);
    }
}

extern "C" void kernel_launch(void* const* d_in, const int* in_sizes, int n_in,
                              void* d_out, int out_size, void* d_ws, size_t ws_size,
                              hipStream_t stream)
{
    const float* vam = (const float*)d_in[0];   // [4096, 16384] f32
    const float* G   = (const float*)d_in[1];   // [16384, 16384] f32
    const int*   kn  = (const int*)d_in[2];     // scalar int (10)
    float* out = (float*)d_out;                 // [16384, 16384] f32

    // workspace layout
    int*   dv    = (int*)d_ws;                               // 16384 ints
    float* invdv = (float*)((char*)d_ws + (size_t)VN * 4);   // 16384 floats
    int*   topk  = (int*)((char*)d_ws + (size_t)VN * 8);     // up to 4096*32 ints

    hipMemsetAsync(dv, 0, VN * sizeof(int), stream);
    topk_dv_kernel<<<EN, TPB, 0, stream>>>(vam, kn, dv, topk);
    invdv_kernel<<<VN / 256, 256, 0, stream>>>(dv, invdv);
    blend_kernel<<<BLEND_BLOCKS, TPB, 0, stream>>>((const f32x4*)G, (f32x4*)out);
    scatter_kernel<<<EN, 128, 0, stream>>>(topk, invdv, kn, out);
}

// Round 5
// 536.213 us; speedup vs baseline: 1.1663x; 1.1663x over previous
//
#include <hip/hip_runtime.h>
#include <math.h>

// Problem constants (shapes fixed by setup_inputs: e_n=4096, v_n=16384, kn=10)
#define VN 16384
#define EN 4096
#define TPB 256
#define CHUNKS 16      // 16 x float4 per thread = 64 elems; 256 threads * 64 = 16384
#define NBLEND 8192    // blend blocks inside the fused kernel
#define NBLOCKS (EN + NBLEND)  // 12288

typedef float f32x4 __attribute__((ext_vector_type(4)));

// ---------------------------------------------------------------------------
// Fused kernel (R2 structure, known 524 us): blocks with bid%3==0 do per-row
// top-k, the other 2/3 stream out = 0.5*G. Interleaving hides the top-k work
// under the memory stream.
//
// R5 change (one variable vs R2): G is read with NON-TEMPORAL loads only.
// Theory: the G read stream and the out write stream thrash the 4MiB/XCD L2
// (each allocation evicts the other stream's lines); NT loads keep G out of
// L2 so the store stream owns it. Stores stay NORMAL (R4 showed NT stores
// regress). If this is the limiter: fused 509 -> ~450. If neutral: mixed
// r+w DRAM rate ~4.7 TB/s is the wall.
//
// Top-k: iterative selection, cached per-thread local argmax, owner-only
// rescan. Tie-break = (max value, lowest index), matching jax.lax.top_k;
// softmax is monotone so top-k of raw logits == top-k of double-softmax.
// ---------------------------------------------------------------------------
__global__ __launch_bounds__(TPB) void fused_kernel(
    const float* __restrict__ vam, const f32x4* __restrict__ g,
    const int* __restrict__ kn_ptr,
    int* __restrict__ dv, int* __restrict__ topk, f32x4* __restrict__ out)
{
    const int bid = blockIdx.x;
    const int t = threadIdx.x;

    if (bid % 3 != 0) {
        // ---------------- blend path: out = 0.5 * G ----------------
        const int blendId = 2 * (bid / 3) + (bid % 3 - 1);   // 0..NBLEND-1
        const long long n4 = (long long)VN * VN / 4;
        long long i = (long long)blendId * TPB + t;
        const long long stride = (long long)NBLEND * TPB;
        for (; i < n4; i += stride) {
            f32x4 x = __builtin_nontemporal_load(&g[i]);   // NT read: keep G out of L2
            out[i] = x * 0.5f;                              // normal store
        }
        return;
    }

    // ---------------- top-k path ----------------
    const int e = bid / 3;                 // 0..EN-1
    const float* row = vam + (size_t)e * VN;

    // Stage the row into registers: thread t owns elements c*1024 + 4t + j
    float v[CHUNKS][4];
#pragma unroll
    for (int c = 0; c < CHUNKS; ++c) {
        const float4 f = *reinterpret_cast<const float4*>(row + c * (TPB * 4) + t * 4);
        v[c][0] = f.x; v[c][1] = f.y; v[c][2] = f.z; v[c][3] = f.w;
    }

    int kn = kn_ptr[0];
    if (kn > 32) kn = 32;   // workspace guard

    __shared__ unsigned long long wred[TPB / 64];
    __shared__ int bcast;

    // cached local best; strict > keeps the lowest index on exact ties
    float bv = -INFINITY;
    int   bi = 0;
#pragma unroll
    for (int c = 0; c < CHUNKS; ++c) {
#pragma unroll
        for (int j = 0; j < 4; ++j) {
            const int gi = c * (TPB * 4) + t * 4 + j;
            if (v[c][j] > bv) { bv = v[c][j]; bi = gi; }
        }
    }

    for (int r = 0; r < kn; ++r) {
        // pack (value, index): u64 max == (max value, min index)
        unsigned int uv = __float_as_uint(bv);
        uv = (uv & 0x80000000u) ? ~uv : (uv | 0x80000000u);  // order-preserving
        unsigned long long key =
            ((unsigned long long)uv << 32) | (unsigned int)(~(unsigned int)bi);

#pragma unroll
        for (int s = 1; s < 64; s <<= 1) {
            const unsigned long long o = __shfl_xor(key, s, 64);
            if (o > key) key = o;
        }
        if ((t & 63) == 0) wred[t >> 6] = key;
        __syncthreads();
        if (t == 0) {
            unsigned long long kmax = wred[0];
#pragma unroll
            for (int w = 1; w < TPB / 64; ++w) if (wred[w] > kmax) kmax = wred[w];
            const int wi = (int)(~(unsigned int)(kmax & 0xffffffffull));
            bcast = wi;
            topk[(size_t)e * kn + r] = wi;
            atomicAdd(dv + wi, 1);
        }
        __syncthreads();
        const int wi = bcast;

        // only the owner thread pays the removal + rescan
        if (((wi >> 2) & (TPB - 1)) == t) {
#pragma unroll
            for (int c = 0; c < CHUNKS; ++c) {
#pragma unroll
                for (int j = 0; j < 4; ++j) {
                    const int gi = c * (TPB * 4) + t * 4 + j;
                    if (gi == wi) v[c][j] = -INFINITY;
                }
            }
            bv = -INFINITY; bi = 0;
#pragma unroll
            for (int c = 0; c < CHUNKS; ++c) {
#pragma unroll
                for (int j = 0; j < 4; ++j) {
                    const int gi = c * (TPB * 4) + t * 4 + j;
                    if (v[c][j] > bv) { bv = v[c][j]; bi = gi; }
                }
            }
        }
        __syncthreads();  // protect wred/bcast reuse next round
    }
}

// invDV[v] = DV[v] > 0 ? DV[v]^-0.5 : 0
__global__ void invdv_kernel(const int* __restrict__ dv, float* __restrict__ invdv)
{
    const int v = blockIdx.x * blockDim.x + threadIdx.x;
    if (v < VN) {
        const int d = dv[v];
        invdv[v] = d > 0 ? 1.0f / sqrtf((float)d) : 0.0f;
    }
}

// out[a][b] += 0.5 * invDV[a]*invDV[b]*(1/kn) for every pair (a,b) in each
// edge's top-k set (includes a==b, both orders -> symmetric, diag included).
__global__ void scatter_kernel(const int* __restrict__ topk,
                               const float* __restrict__ invdv,
                               const int* __restrict__ kn_ptr,
                               float* __restrict__ out)
{
    const int e = blockIdx.x;
    int kn = kn_ptr[0];
    if (kn > 32) kn = 32;
    const int total = kn * kn;
    const float inv_de = 1.0f / (float)kn;
    for (int p = threadIdx.x; p < total; p += blockDim.x) {
        const int a = topk[(size_t)e * kn + p / kn];
        const int b = topk[(size_t)e * kn + p % kn];
        const float c = 0.5f * invdv[a] * invdv[b] * inv_de;
        atomicAdd(out + (size_t)a * VN + b, c);
    }
}

extern "C" void kernel_launch(void* const* d_in, const int* in_sizes, int n_in,
                              void* d_out, int out_size, void* d_ws, size_t ws_size,
                              hipStream_t stream)
{
    const float* vam = (const float*)d_in[0];   // [4096, 16384] f32
    const float* G   = (const float*)d_in[1];   // [16384, 16384] f32
    const int*   kn  = (const int*)d_in[2];     // scalar int (10)
    float* out = (float*)d_out;                 // [16384, 16384] f32

    // workspace layout
    int*   dv    = (int*)d_ws;                               // 16384 ints
    float* invdv = (float*)((char*)d_ws + (size_t)VN * 4);   // 16384 floats
    int*   topk  = (int*)((char*)d_ws + (size_t)VN * 8);     // up to 4096*32 ints

    hipMemsetAsync(dv, 0, VN * sizeof(int), stream);
    fused_kernel<<<NBLOCKS, TPB, 0, stream>>>(vam, (const f32x4*)G, kn, dv, topk,
                                              (f32x4*)out);
    invdv_kernel<<<VN / 256, 256, 0, stream>>>(dv, invdv);
    scatter_kernel<<<EN, 128, 0, stream>>>(topk, invdv, kn, out);
}

// Round 6
// 496.905 us; speedup vs baseline: 1.2585x; 1.0791x over previous
//
#include <hip/hip_runtime.h>
#include <math.h>

// Problem constants (shapes fixed by setup_inputs: e_n=4096, v_n=16384, kn=10)
#define VN 16384
#define EN 4096
#define TPB 256
#define CHUNKS 16      // 16 x float4 per thread = 64 elems; 256 threads * 64 = 16384
#define NBLEND 8192    // blend blocks inside the fused kernel
#define NBLOCKS (EN + NBLEND)  // 12288

typedef float f32x4 __attribute__((ext_vector_type(4)));

// ---------------------------------------------------------------------------
// Fused kernel (R2-exact structure, the 524-us champion): blocks with
// bid%3==0 do per-row top-k, the other 2/3 stream out = 0.5*G. Interleaving
// hides the top-k work under the memory stream.
//
// Blend stream rate note (R2-R5 ablation): plain loop / 8-deep ILP / NT
// stores / NT loads / 2048-block grid all land at ~4.7-4.8 TB/s for this
// 1:1 read+write mix, vs 6.5 TB/s for the harness's write-only fills on the
// same buffers -> mixed-direction DRAM streams are the wall, not MLP, not
// L2 policy. Keep the simplest form.
//
// Top-k: iterative selection, cached per-thread local argmax, owner-only
// rescan. Tie-break = (max value, lowest index), matching jax.lax.top_k;
// softmax is monotone so top-k of raw logits == top-k of double-softmax.
// ---------------------------------------------------------------------------
__global__ __launch_bounds__(TPB) void fused_kernel(
    const float* __restrict__ vam, const f32x4* __restrict__ g,
    const int* __restrict__ kn_ptr,
    int* __restrict__ dv, int* __restrict__ topk, f32x4* __restrict__ out)
{
    const int bid = blockIdx.x;
    const int t = threadIdx.x;

    if (bid % 3 != 0) {
        // ---------------- blend path: out = 0.5 * G ----------------
        const int blendId = 2 * (bid / 3) + (bid % 3 - 1);   // 0..NBLEND-1
        const long long n4 = (long long)VN * VN / 4;
        long long i = (long long)blendId * TPB + t;
        const long long stride = (long long)NBLEND * TPB;
        for (; i < n4; i += stride) {
            f32x4 x = g[i];
            out[i] = x * 0.5f;
        }
        return;
    }

    // ---------------- top-k path ----------------
    const int e = bid / 3;                 // 0..EN-1
    const float* row = vam + (size_t)e * VN;

    // Stage the row into registers: thread t owns elements c*1024 + 4t + j
    float v[CHUNKS][4];
#pragma unroll
    for (int c = 0; c < CHUNKS; ++c) {
        const float4 f = *reinterpret_cast<const float4*>(row + c * (TPB * 4) + t * 4);
        v[c][0] = f.x; v[c][1] = f.y; v[c][2] = f.z; v[c][3] = f.w;
    }

    int kn = kn_ptr[0];
    if (kn > 32) kn = 32;   // workspace guard

    __shared__ unsigned long long wred[TPB / 64];
    __shared__ int bcast;

    // cached local best; strict > keeps the lowest index on exact ties
    float bv = -INFINITY;
    int   bi = 0;
#pragma unroll
    for (int c = 0; c < CHUNKS; ++c) {
#pragma unroll
        for (int j = 0; j < 4; ++j) {
            const int gi = c * (TPB * 4) + t * 4 + j;
            if (v[c][j] > bv) { bv = v[c][j]; bi = gi; }
        }
    }

    for (int r = 0; r < kn; ++r) {
        // pack (value, index): u64 max == (max value, min index)
        unsigned int uv = __float_as_uint(bv);
        uv = (uv & 0x80000000u) ? ~uv : (uv | 0x80000000u);  // order-preserving
        unsigned long long key =
            ((unsigned long long)uv << 32) | (unsigned int)(~(unsigned int)bi);

#pragma unroll
        for (int s = 1; s < 64; s <<= 1) {
            const unsigned long long o = __shfl_xor(key, s, 64);
            if (o > key) key = o;
        }
        if ((t & 63) == 0) wred[t >> 6] = key;
        __syncthreads();
        if (t == 0) {
            unsigned long long kmax = wred[0];
#pragma unroll
            for (int w = 1; w < TPB / 64; ++w) if (wred[w] > kmax) kmax = wred[w];
            const int wi = (int)(~(unsigned int)(kmax & 0xffffffffull));
            bcast = wi;
            topk[(size_t)e * kn + r] = wi;
            atomicAdd(dv + wi, 1);
        }
        __syncthreads();
        const int wi = bcast;

        // only the owner thread pays the removal + rescan
        if (((wi >> 2) & (TPB - 1)) == t) {
#pragma unroll
            for (int c = 0; c < CHUNKS; ++c) {
#pragma unroll
                for (int j = 0; j < 4; ++j) {
                    const int gi = c * (TPB * 4) + t * 4 + j;
                    if (gi == wi) v[c][j] = -INFINITY;
                }
            }
            bv = -INFINITY; bi = 0;
#pragma unroll
            for (int c = 0; c < CHUNKS; ++c) {
#pragma unroll
                for (int j = 0; j < 4; ++j) {
                    const int gi = c * (TPB * 4) + t * 4 + j;
                    if (v[c][j] > bv) { bv = v[c][j]; bi = gi; }
                }
            }
        }
        __syncthreads();  // protect wred/bcast reuse next round
    }
}

// ---------------------------------------------------------------------------
// out[a][b] += 0.5 * DV[a]^-0.5 * DV[b]^-0.5 * (1/kn) for every pair (a,b)
// in each edge's top-k set. invDV computed inline (rsqrtf): every index in a
// top-k list has dv >= 1 by construction, so no zero-guard needed; rsqrtf
// error ~1e-6 relative on increments <= 0.05, far below the 0.054 threshold.
// Must run AFTER the blend (plain store vs atomicAdd ordering).
// ---------------------------------------------------------------------------
__global__ void scatter_kernel(const int* __restrict__ topk,
                               const int* __restrict__ dv,
                               const int* __restrict__ kn_ptr,
                               float* __restrict__ out)
{
    const int e = blockIdx.x;
    int kn = kn_ptr[0];
    if (kn > 32) kn = 32;
    const int total = kn * kn;
    const float inv_de = 1.0f / (float)kn;
    for (int p = threadIdx.x; p < total; p += blockDim.x) {
        const int a = topk[(size_t)e * kn + p / kn];
        const int b = topk[(size_t)e * kn + p % kn];
        const float c = 0.5f * inv_de * rsqrtf((float)dv[a]) * rsqrtf((float)dv[b]);
        atomicAdd(out + (size_t)a * VN + b, c);
    }
}

extern "C" void kernel_launch(void* const* d_in, const int* in_sizes, int n_in,
                              void* d_out, int out_size, void* d_ws, size_t ws_size,
                              hipStream_t stream)
{
    const float* vam = (const float*)d_in[0];   // [4096, 16384] f32
    const float* G   = (const float*)d_in[1];   // [16384, 16384] f32
    const int*   kn  = (const int*)d_in[2];     // scalar int (10)
    float* out = (float*)d_out;                 // [16384, 16384] f32

    // workspace layout
    int* dv   = (int*)d_ws;                             // 16384 ints
    int* topk = (int*)((char*)d_ws + (size_t)VN * 4);   // up to 4096*32 ints

    hipMemsetAsync(dv, 0, VN * sizeof(int), stream);
    fused_kernel<<<NBLOCKS, TPB, 0, stream>>>(vam, (const f32x4*)G, kn, dv, topk,
                                              (f32x4*)out);
    scatter_kernel<<<EN, 128, 0, stream>>>(topk, dv, kn, out);
}